// Round 6
// baseline (322.944 us; speedup 1.0000x reference)
//
#include <hip/hip_runtime.h>
#include <hip/hip_cooperative_groups.h>

namespace cg = cooperative_groups;

// Problem constants (match reference)
#define BB 8
#define NN 1024
#define NE 32768
#define EFF 4
#define DD 64
#define ROWCAP 128  // bucket capacity per row (mean fill ~32, P(overflow) ~ 1e-36)
#define NBLK 1024
#define NTHR 256    // NBLK*NTHR = 262144 = BB*NE exactly (1 edge/thread in P1)

struct RowState {
    float4 a0, a1;   // rs .* val for this lane's two bucket entries (0 if not winner)
    float selfc;     // sum_f rs_f^2  (self-loop coefficient)
    int dst0, dst1;
    bool w0, w1;     // winner flags
};

// ---------------------------------------------------------------------------
// Fused cooperative kernel: P0 zero counters | P1 scatter | P2 dedup+deg+rsqrt
// (2 rows per wave, LDS table per wave, results kept in registers) | P3 output.
// grid.sync() between phases replaces 3 kernel boundaries; P2->P3 passes the
// winner set in registers (no bucket compaction, no wcnt, no re-reads).
// ---------------------------------------------------------------------------
__global__ __launch_bounds__(NTHR) void k_fused(
    const int* __restrict__ eidx, const float* __restrict__ evals,
    const float* __restrict__ Wh, float* __restrict__ out,
    int* __restrict__ cnt, unsigned int* __restrict__ bucket,
    float4* __restrict__ rdT)
{
    cg::grid_group grid = cg::this_grid();
    __shared__ int table[NTHR / 64][1024];  // 16 KB/block, one table per wave
    const int tid = blockIdx.x * NTHR + threadIdx.x;  // 0..262143
    const int lane = threadIdx.x & 63;
    int* tab = table[threadIdx.x >> 6];
    const int wv = tid >> 6;  // 0..4095; this wave owns rows wv and wv+4096

    // ---- P0: zero per-row counters ----
    if (tid < BB * NN) cnt[tid] = 0;
    grid.sync();

    // ---- P1: scatter, exactly one edge per thread ----
    {
        const int b = tid >> 15;
        const int e = tid & (NE - 1);
        const int src = eidx[b * 2 * NE + e];
        const int dst = eidx[b * 2 * NE + NE + e];
        const int row = b * NN + src;
        const int slot = atomicAdd(&cnt[row], 1);
        if (slot < ROWCAP)
            bucket[row * ROWCAP + slot] = ((unsigned)e << 10) | (unsigned)dst;
    }
    grid.sync();

    // ---- P2: dedup + degree + rsqrt, two rows per wave, state in registers ----
    RowState st[2];
#pragma unroll
    for (int half = 0; half < 2; ++half) {
        const int row = wv + half * (BB * NN / 2);
        const int b = row >> 10;
        // re-init this wave's LDS table (wave-private: no __syncthreads needed)
#pragma unroll
        for (int i = 0; i < 16; ++i) tab[i * 64 + lane] = -1;
        int c = cnt[row];
        c = (c < ROWCAP) ? c : ROWCAP;
        const unsigned* brow = bucket + row * ROWCAP;
        const bool h0 = lane < c, h1 = 64 + lane < c;
        const unsigned ent0 = h0 ? brow[lane] : 0u;
        const unsigned ent1 = h1 ? brow[64 + lane] : 0u;
        if (h0) atomicMax(&tab[ent0 & 1023], (int)(ent0 >> 10));
        if (h1) atomicMax(&tab[ent1 & 1023], (int)(ent1 >> 10));
        const bool v0 = h0 && (tab[ent0 & 1023] == (int)(ent0 >> 10));
        const bool v1 = h1 && (tab[ent1 & 1023] == (int)(ent1 >> 10));
        float4 val0 = make_float4(0.f, 0.f, 0.f, 0.f);
        float4 val1 = make_float4(0.f, 0.f, 0.f, 0.f);
        if (v0) val0 = *(const float4*)&evals[(b * NE + (int)(ent0 >> 10)) * EFF];
        if (v1) val1 = *(const float4*)&evals[(b * NE + (int)(ent1 >> 10)) * EFF];
        float s0 = val0.x + val1.x, s1 = val0.y + val1.y;
        float s2 = val0.z + val1.z, s3 = val0.w + val1.w;
#pragma unroll
        for (int off = 32; off; off >>= 1) {
            s0 += __shfl_xor(s0, off);
            s1 += __shfl_xor(s1, off);
            s2 += __shfl_xor(s2, off);
            s3 += __shfl_xor(s3, off);
        }
        float4 rs;
        rs.x = rsqrtf(1.f + s0);
        rs.y = rsqrtf(1.f + s1);
        rs.z = rsqrtf(1.f + s2);
        rs.w = rsqrtf(1.f + s3);
        if (lane == 0) rdT[row] = rs;
        st[half].selfc = rs.x * rs.x + rs.y * rs.y + rs.z * rs.z + rs.w * rs.w;
        st[half].a0 = make_float4(rs.x * val0.x, rs.y * val0.y, rs.z * val0.z, rs.w * val0.w);
        st[half].a1 = make_float4(rs.x * val1.x, rs.y * val1.y, rs.z * val1.z, rs.w * val1.w);
        st[half].dst0 = (int)(ent0 & 1023);
        st[half].dst1 = (int)(ent1 & 1023);
        st[half].w0 = v0;
        st[half].w1 = v1;
    }
    grid.sync();

    // ---- P3: output, two rows per wave, winner set from registers ----
#pragma unroll
    for (int half = 0; half < 2; ++half) {
        const int row = wv + half * (BB * NN / 2);
        const int b = row >> 10;
        float acc = st[half].selfc * Wh[row * DD + lane];
        float cf0 = 0.f, cf1 = 0.f;
        if (st[half].w0) {
            float4 rd = rdT[(b << 10) | st[half].dst0];
            cf0 = st[half].a0.x * rd.x + st[half].a0.y * rd.y +
                  st[half].a0.z * rd.z + st[half].a0.w * rd.w;
        }
        if (st[half].w1) {
            float4 rd = rdT[(b << 10) | st[half].dst1];
            cf1 = st[half].a1.x * rd.x + st[half].a1.y * rd.y +
                  st[half].a1.z * rd.z + st[half].a1.w * rd.w;
        }
        unsigned long long m = __ballot(st[half].w0);
        while (m) {
            const int j = __ffsll(m) - 1;
            m &= m - 1;
            const float c = __shfl(cf0, j);
            const int d = __shfl(st[half].dst0, j);
            acc += c * Wh[((b << 10) | d) * DD + lane];
        }
        m = __ballot(st[half].w1);
        while (m) {
            const int j = __ffsll(m) - 1;
            m &= m - 1;
            const float c = __shfl(cf1, j);
            const int d = __shfl(st[half].dst1, j);
            acc += c * Wh[((b << 10) | d) * DD + lane];
        }
        out[row * DD + lane] = acc * (1.0f / EFF);
    }
}

// ===========================================================================
// Fallback path (proven R5 kernels) if cooperative residency isn't available.
// ===========================================================================
__global__ void k_zero(int* __restrict__ cnt) {
    int t = blockIdx.x * blockDim.x + threadIdx.x;
    if (t < BB * NN) cnt[t] = 0;
}

__global__ void k_scatter(const int* __restrict__ eidx, int* __restrict__ cnt,
                          unsigned int* __restrict__ bucket) {
    int t = blockIdx.x * blockDim.x + threadIdx.x;
    if (t >= BB * NE) return;
    int b = t / NE;
    int e = t - b * NE;
    int src = eidx[b * 2 * NE + e];
    int dst = eidx[b * 2 * NE + NE + e];
    int row = b * NN + src;
    int slot = atomicAdd(&cnt[row], 1);
    if (slot < ROWCAP) bucket[(size_t)row * ROWCAP + slot] = ((unsigned)e << 10) | (unsigned)dst;
}

__global__ __launch_bounds__(256) void k_row_deg(const float* __restrict__ evals,
                                                  const int* __restrict__ cnt,
                                                  unsigned int* __restrict__ bucket,
                                                  int* __restrict__ wcnt,
                                                  float4* __restrict__ rdT) {
    __shared__ int table[4][1024];
    int lane = threadIdx.x & 63;
    int wline = threadIdx.x >> 6;
    int wid = (blockIdx.x * blockDim.x + threadIdx.x) >> 6;
    int b = wid >> 10;
    int* tab = table[wline];
#pragma unroll
    for (int i = 0; i < 16; ++i) tab[i * 64 + lane] = -1;
    int c = cnt[wid];
    c = (c < ROWCAP) ? c : ROWCAP;
    unsigned int* brow = bucket + (size_t)wid * ROWCAP;
    bool h0 = lane < c, h1 = 64 + lane < c;
    unsigned int e0 = h0 ? brow[lane] : 0u;
    unsigned int e1 = h1 ? brow[64 + lane] : 0u;
    __syncthreads();
    if (h0) atomicMax(&tab[e0 & 1023], (int)(e0 >> 10));
    if (h1) atomicMax(&tab[e1 & 1023], (int)(e1 >> 10));
    __syncthreads();
    bool w0 = h0 && (tab[e0 & 1023] == (int)(e0 >> 10));
    bool w1 = h1 && (tab[e1 & 1023] == (int)(e1 >> 10));
    float s0 = 0.f, s1 = 0.f, s2 = 0.f, s3 = 0.f;
    if (w0) {
        float4 v = *(const float4*)&evals[((size_t)b * NE + (e0 >> 10)) * EFF];
        s0 += v.x; s1 += v.y; s2 += v.z; s3 += v.w;
    }
    if (w1) {
        float4 v = *(const float4*)&evals[((size_t)b * NE + (e1 >> 10)) * EFF];
        s0 += v.x; s1 += v.y; s2 += v.z; s3 += v.w;
    }
#pragma unroll
    for (int off = 32; off; off >>= 1) {
        s0 += __shfl_xor(s0, off);
        s1 += __shfl_xor(s1, off);
        s2 += __shfl_xor(s2, off);
        s3 += __shfl_xor(s3, off);
    }
    unsigned long long lt = (1ull << lane) - 1ull;
    unsigned long long m0 = __ballot(w0);
    if (w0) brow[__popcll(m0 & lt)] = e0;
    int n0 = __popcll(m0);
    unsigned long long m1 = __ballot(w1);
    if (w1) brow[n0 + __popcll(m1 & lt)] = e1;
    if (lane == 0) {
        wcnt[wid] = n0 + __popcll(m1);
        float4 r;
        r.x = rsqrtf(1.f + s0);
        r.y = rsqrtf(1.f + s1);
        r.z = rsqrtf(1.f + s2);
        r.w = rsqrtf(1.f + s3);
        rdT[wid] = r;
    }
}

__global__ __launch_bounds__(256) void k_row_out(const float* __restrict__ evals,
                                                  const unsigned int* __restrict__ bucket,
                                                  const int* __restrict__ wcnt,
                                                  const float4* __restrict__ rdT,
                                                  const float* __restrict__ Wh,
                                                  float* __restrict__ out) {
    int wid = (blockIdx.x * blockDim.x + threadIdx.x) >> 6;
    int lane = threadIdx.x & 63;
    int b = wid >> 10;
    float4 rs = rdT[wid];
    float acc = (rs.x * rs.x + rs.y * rs.y + rs.z * rs.z + rs.w * rs.w) *
                Wh[(size_t)wid * DD + lane];
    int c = wcnt[wid];
    const unsigned int* brow = bucket + (size_t)wid * ROWCAP;
    for (int i = 0; i < c; ++i) {
        unsigned int h = brow[i];
        int dst = h & 1023;
        int e = h >> 10;
        float4 val = *(const float4*)&evals[((size_t)b * NE + e) * EFF];
        float4 rdd = rdT[b * NN + dst];
        float cf = rs.x * val.x * rdd.x + rs.y * val.y * rdd.y +
                   rs.z * val.z * rdd.z + rs.w * val.w * rdd.w;
        acc += cf * Wh[((size_t)b * NN + dst) * DD + lane];
    }
    out[(size_t)wid * DD + lane] = acc * (1.0f / EFF);
}

extern "C" void kernel_launch(void* const* d_in, const int* in_sizes, int n_in,
                              void* d_out, int out_size, void* d_ws, size_t ws_size,
                              hipStream_t stream) {
    const float* Wh = (const float*)d_in[0];
    const int* eidx = (const int*)d_in[1];
    const float* evals = (const float*)d_in[2];
    float* out = (float*)d_out;

    // Workspace layout
    char* p = (char*)d_ws;
    int* cnt = (int*)p;       p += (size_t)BB * NN * sizeof(int);     // 32 KB
    int* wcnt = (int*)p;      p += (size_t)BB * NN * sizeof(int);     // 32 KB
    float4* rdT = (float4*)p; p += (size_t)BB * NN * sizeof(float4);  // 128 KB
    unsigned int* bucket = (unsigned int*)p;                          // 4 MiB

    // Cooperative path needs 4 co-resident blocks/CU (1024 blocks on 256 CUs).
    int maxb = 0;
    hipOccupancyMaxActiveBlocksPerMultiprocessor(&maxb, (const void*)k_fused, NTHR, 0);
    if (maxb >= NBLK / 256) {
        void* args[] = {(void*)&eidx, (void*)&evals, (void*)&Wh, (void*)&out,
                        (void*)&cnt, (void*)&bucket, (void*)&rdT};
        hipLaunchCooperativeKernel((const void*)k_fused, dim3(NBLK), dim3(NTHR),
                                   args, 0, stream);
    } else {
        const int T = 256;
        k_zero<<<(BB * NN + T - 1) / T, T, 0, stream>>>(cnt);
        k_scatter<<<(BB * NE + T - 1) / T, T, 0, stream>>>(eidx, cnt, bucket);
        k_row_deg<<<(BB * NN) / 4, T, 0, stream>>>(evals, cnt, bucket, wcnt, rdT);
        k_row_out<<<(BB * NN) / 4, T, 0, stream>>>(evals, bucket, wcnt, rdT, Wh, out);
    }
}

// Round 7
// 67.876 us; speedup vs baseline: 4.7579x; 4.7579x over previous
//
#include <hip/hip_runtime.h>

// Problem constants (match reference)
#define BB 8
#define NN 1024
#define NE 32768
#define EFF 4
#define DD 64
#define CAP 128   // max compacted hits per row (mean ~32, Binomial tail ~1e-40)

// ---------------------------------------------------------------------------
// K0: zero the 32 MiB owner table at full write BW (rocclr fill does 858 GB/s;
//     this does ~6 TB/s with int4 grid-stride stores).
// ---------------------------------------------------------------------------
__global__ __launch_bounds__(256) void k_zero_owner(int4* __restrict__ owner4) {
    const int total = BB * NN * NN / 4;          // 2M int4
    int t = blockIdx.x * blockDim.x + threadIdx.x;
    const int stride = gridDim.x * blockDim.x;
    const int4 m1 = make_int4(-1, -1, -1, -1);
    for (; t < total; t += stride) owner4[t] = m1;
}

// ---------------------------------------------------------------------------
// K1: atomicMax edge-id into owner[b][src][dst] -> last-write-wins dedup.
//     Uncontended in expectation (1M slots, 262K edges); no return-value use.
// ---------------------------------------------------------------------------
__global__ void k_owner_max(const int* __restrict__ eidx, int* __restrict__ owner) {
    int t = blockIdx.x * blockDim.x + threadIdx.x;
    if (t >= BB * NE) return;
    int b = t / NE;
    int e = t - b * NE;
    int src = eidx[b * 2 * NE + e];
    int dst = eidx[b * 2 * NE + NE + e];
    atomicMax(&owner[(size_t)b * NN * NN + src * NN + dst], e);
}

// ---------------------------------------------------------------------------
// K2: wave-per-row scan of owner. Produces, with ZERO atomics:
//   - compacted hit list hits[row][0..cnt): (dst << 16) | e
//   - cnts[row]
//   - rdT[b][src] = float4 of rsqrt(1 + sum_winners val_f)  (fused rsqrt)
// ---------------------------------------------------------------------------
__global__ __launch_bounds__(256) void k_row_deg(const int* __restrict__ owner,
                                                  const float* __restrict__ evals,
                                                  unsigned int* __restrict__ hits,
                                                  int* __restrict__ cnts,
                                                  float4* __restrict__ rdT) {
    int wid = (blockIdx.x * blockDim.x + threadIdx.x) >> 6;  // row id = b*NN+src
    int lane = threadIdx.x & 63;
    if (wid >= BB * NN) return;
    int b = wid >> 10;

    const int4* row = (const int4*)(owner + (size_t)wid * NN);
    unsigned int* hrow = hits + (size_t)wid * CAP;

    float s0 = 0.f, s1 = 0.f, s2 = 0.f, s3 = 0.f;
    int cnt = 0;
#pragma unroll
    for (int k = 0; k < 4; ++k) {
        int4 v = row[k * 64 + lane];  // coalesced 1 KB per wave
#pragma unroll
        for (int j = 0; j < 4; ++j) {
            int vj = (j == 0) ? v.x : (j == 1) ? v.y : (j == 2) ? v.z : v.w;
            bool hit = vj >= 0;
            unsigned long long m = __ballot(hit);
            if (hit) {
                int rank = __popcll(m & ((1ull << lane) - 1ull));
                int dst = k * 256 + lane * 4 + j;
                int slot = cnt + rank;
                if (slot < CAP) hrow[slot] = ((unsigned)dst << 16) | (unsigned)vj;
                float4 val = *(const float4*)&evals[((size_t)b * NE + vj) * EFF];
                s0 += val.x; s1 += val.y; s2 += val.z; s3 += val.w;
            }
            cnt += __popcll(m);
        }
    }
#pragma unroll
    for (int off = 32; off; off >>= 1) {
        s0 += __shfl_xor(s0, off);
        s1 += __shfl_xor(s1, off);
        s2 += __shfl_xor(s2, off);
        s3 += __shfl_xor(s3, off);
    }
    if (lane == 0) {
        cnts[wid] = (cnt < CAP) ? cnt : CAP;
        float4 r;
        r.x = rsqrtf(1.f + s0);
        r.y = rsqrtf(1.f + s1);
        r.z = rsqrtf(1.f + s2);
        r.w = rsqrtf(1.f + s3);
        rdT[wid] = r;
    }
}

// ---------------------------------------------------------------------------
// K3: wave-per-row output over the compact hit list. All loads except Wh are
//     wave-uniform broadcasts; Wh[dst][lane] coalesced 256B. No atomics.
// ---------------------------------------------------------------------------
__global__ __launch_bounds__(256) void k_row_out(const float* __restrict__ evals,
                                                  const unsigned int* __restrict__ hits,
                                                  const int* __restrict__ cnts,
                                                  const float4* __restrict__ rdT,
                                                  const float* __restrict__ Wh,
                                                  float* __restrict__ out) {
    int wid = (blockIdx.x * blockDim.x + threadIdx.x) >> 6;  // row id = b*NN+src
    int lane = threadIdx.x & 63;
    if (wid >= BB * NN) return;
    int b = wid >> 10;

    float4 rs = rdT[wid];  // wave-uniform
    float acc = (rs.x * rs.x + rs.y * rs.y + rs.z * rs.z + rs.w * rs.w) *
                Wh[(size_t)wid * DD + lane];

    int c = cnts[wid];
    const unsigned int* hrow = hits + (size_t)wid * CAP;
    for (int i = 0; i < c; ++i) {
        unsigned int h = hrow[i];          // uniform broadcast
        int dst = h >> 16;
        int e = h & 0xFFFF;
        float4 val = *(const float4*)&evals[((size_t)b * NE + e) * EFF];  // uniform
        float4 rdd = rdT[b * NN + dst];                                   // uniform
        float cf = rs.x * val.x * rdd.x + rs.y * val.y * rdd.y +
                   rs.z * val.z * rdd.z + rs.w * val.w * rdd.w;
        acc += cf * Wh[((size_t)b * NN + dst) * DD + lane];
    }
    out[(size_t)wid * DD + lane] = acc * (1.0f / EFF);
}

extern "C" void kernel_launch(void* const* d_in, const int* in_sizes, int n_in,
                              void* d_out, int out_size, void* d_ws, size_t ws_size,
                              hipStream_t stream) {
    const float* Wh = (const float*)d_in[0];
    const int* eidx = (const int*)d_in[1];
    const float* evals = (const float*)d_in[2];
    float* out = (float*)d_out;

    // Workspace layout
    char* p = (char*)d_ws;
    int* owner = (int*)p;                  p += (size_t)BB * NN * NN * sizeof(int);   // 32 MiB
    float4* rdT = (float4*)p;              p += (size_t)BB * NN * sizeof(float4);     // 128 KiB
    unsigned int* hits = (unsigned int*)p; p += (size_t)BB * NN * CAP * sizeof(int);  // 4 MiB
    int* cnts = (int*)p;

    const int T = 256;
    k_zero_owner<<<2048, T, 0, stream>>>((int4*)owner);
    k_owner_max<<<(BB * NE + T - 1) / T, T, 0, stream>>>(eidx, owner);
    k_row_deg<<<(BB * NN) / 4, T, 0, stream>>>(owner, evals, hits, cnts, rdT);
    k_row_out<<<(BB * NN) / 4, T, 0, stream>>>(evals, hits, cnts, rdT, Wh, out);
}

// Round 8
// 42.724 us; speedup vs baseline: 7.5589x; 1.5887x over previous
//
#include <hip/hip_runtime.h>

// Problem constants (match reference)
#define BB 8
#define NN 1024
#define NE 32768
#define EFF 4
#define DD 64
#define ROWCAP 128  // bucket capacity per row (mean fill ~32, P(overflow) ~ 1e-36)

// ---------------------------------------------------------------------------
// K0: zero the per-row counters (32 KB).
// ---------------------------------------------------------------------------
__global__ void k_zero(int* __restrict__ cnt) {
    int t = blockIdx.x * blockDim.x + threadIdx.x;
    if (t < BB * NN) cnt[t] = 0;
}

// ---------------------------------------------------------------------------
// K1: scatter edges into per-(b,src) buckets. Entry packs (e << 10) | dst.
// ---------------------------------------------------------------------------
__global__ void k_scatter(const int* __restrict__ eidx, int* __restrict__ cnt,
                          unsigned int* __restrict__ bucket) {
    int t = blockIdx.x * blockDim.x + threadIdx.x;
    if (t >= BB * NE) return;
    int b = t / NE;
    int e = t - b * NE;
    int src = eidx[b * 2 * NE + e];
    int dst = eidx[b * 2 * NE + NE + e];
    int row = b * NN + src;
    int slot = atomicAdd(&cnt[row], 1);
    if (slot < ROWCAP) bucket[(size_t)row * ROWCAP + slot] = ((unsigned)e << 10) | (unsigned)dst;
}

// ---------------------------------------------------------------------------
// K2: wave-per-row dedup + degree + rsqrt (unchanged from R5).
// ---------------------------------------------------------------------------
__global__ __launch_bounds__(256) void k_row_deg(const float* __restrict__ evals,
                                                  const int* __restrict__ cnt,
                                                  unsigned int* __restrict__ bucket,
                                                  int* __restrict__ wcnt,
                                                  float4* __restrict__ rdT) {
    __shared__ int table[4][1024];
    int lane = threadIdx.x & 63;
    int wline = threadIdx.x >> 6;
    int wid = (blockIdx.x * blockDim.x + threadIdx.x) >> 6;
    int b = wid >> 10;
    int* tab = table[wline];
#pragma unroll
    for (int i = 0; i < 16; ++i) tab[i * 64 + lane] = -1;
    int c = cnt[wid];
    c = (c < ROWCAP) ? c : ROWCAP;
    unsigned int* brow = bucket + (size_t)wid * ROWCAP;
    bool h0 = lane < c, h1 = 64 + lane < c;
    unsigned int e0 = h0 ? brow[lane] : 0u;
    unsigned int e1 = h1 ? brow[64 + lane] : 0u;
    __syncthreads();
    if (h0) atomicMax(&tab[e0 & 1023], (int)(e0 >> 10));
    if (h1) atomicMax(&tab[e1 & 1023], (int)(e1 >> 10));
    __syncthreads();
    bool w0 = h0 && (tab[e0 & 1023] == (int)(e0 >> 10));
    bool w1 = h1 && (tab[e1 & 1023] == (int)(e1 >> 10));
    float s0 = 0.f, s1 = 0.f, s2 = 0.f, s3 = 0.f;
    if (w0) {
        float4 v = *(const float4*)&evals[((size_t)b * NE + (e0 >> 10)) * EFF];
        s0 += v.x; s1 += v.y; s2 += v.z; s3 += v.w;
    }
    if (w1) {
        float4 v = *(const float4*)&evals[((size_t)b * NE + (e1 >> 10)) * EFF];
        s0 += v.x; s1 += v.y; s2 += v.z; s3 += v.w;
    }
#pragma unroll
    for (int off = 32; off; off >>= 1) {
        s0 += __shfl_xor(s0, off);
        s1 += __shfl_xor(s1, off);
        s2 += __shfl_xor(s2, off);
        s3 += __shfl_xor(s3, off);
    }
    unsigned long long lt = (1ull << lane) - 1ull;
    unsigned long long m0 = __ballot(w0);
    if (w0) brow[__popcll(m0 & lt)] = e0;
    int n0 = __popcll(m0);
    unsigned long long m1 = __ballot(w1);
    if (w1) brow[n0 + __popcll(m1 & lt)] = e1;
    if (lane == 0) {
        wcnt[wid] = n0 + __popcll(m1);
        float4 r;
        r.x = rsqrtf(1.f + s0);
        r.y = rsqrtf(1.f + s1);
        r.z = rsqrtf(1.f + s2);
        r.w = rsqrtf(1.f + s3);
        rdT[wid] = r;
    }
}

// ---------------------------------------------------------------------------
// K3: wave-per-row output, latency-flattened.
//     Phase A (parallel): lane i loads hit i, its evals4 and rdT4, computes
//       coefficient cf_i — one memory round-trip for all hits.
//     Phase B: shuffle-broadcast cf/dst; Wh row loads unrolled x8 so up to 8
//       independent 256B loads are in flight (breaks the serial chain).
// ---------------------------------------------------------------------------
__global__ __launch_bounds__(256) void k_row_out(const float* __restrict__ evals,
                                                  const unsigned int* __restrict__ bucket,
                                                  const int* __restrict__ wcnt,
                                                  const float4* __restrict__ rdT,
                                                  const float* __restrict__ Wh,
                                                  float* __restrict__ out) {
    int wid = (blockIdx.x * blockDim.x + threadIdx.x) >> 6;  // row id
    int lane = threadIdx.x & 63;
    int b = wid >> 10;

    float4 rs = rdT[wid];  // wave-uniform
    float acc = (rs.x * rs.x + rs.y * rs.y + rs.z * rs.z + rs.w * rs.w) *
                Wh[(size_t)wid * DD + lane];

    int c = wcnt[wid];
    const unsigned int* brow = bucket + (size_t)wid * ROWCAP;
    const float* WhB = Wh + ((size_t)b << 10) * DD;

    for (int base = 0; base < c; base += 64) {
        int i = base + lane;
        float cf = 0.f;
        int dst = 0;
        if (i < c) {
            unsigned int h = brow[i];       // coalesced: whole hit list in 1 load
            dst = (int)(h & 1023);
            int e = (int)(h >> 10);
            float4 val = *(const float4*)&evals[((size_t)b * NE + e) * EFF];
            float4 rdd = rdT[(b << 10) | dst];
            cf = rs.x * val.x * rdd.x + rs.y * val.y * rdd.y +
                 rs.z * val.z * rdd.z + rs.w * val.w * rdd.w;
        }
        int n = c - base;
        n = (n < 64) ? n : 64;
        int j = 0;
        for (; j + 8 <= n; j += 8) {
            float c0 = __shfl(cf, j+0), c1 = __shfl(cf, j+1);
            float c2 = __shfl(cf, j+2), c3 = __shfl(cf, j+3);
            float c4 = __shfl(cf, j+4), c5 = __shfl(cf, j+5);
            float c6 = __shfl(cf, j+6), c7 = __shfl(cf, j+7);
            int d0 = __shfl(dst, j+0), d1 = __shfl(dst, j+1);
            int d2 = __shfl(dst, j+2), d3 = __shfl(dst, j+3);
            int d4 = __shfl(dst, j+4), d5 = __shfl(dst, j+5);
            int d6 = __shfl(dst, j+6), d7 = __shfl(dst, j+7);
            float w0 = WhB[d0 * DD + lane];
            float w1 = WhB[d1 * DD + lane];
            float w2 = WhB[d2 * DD + lane];
            float w3 = WhB[d3 * DD + lane];
            float w4 = WhB[d4 * DD + lane];
            float w5 = WhB[d5 * DD + lane];
            float w6 = WhB[d6 * DD + lane];
            float w7 = WhB[d7 * DD + lane];
            acc += c0 * w0; acc += c1 * w1; acc += c2 * w2; acc += c3 * w3;
            acc += c4 * w4; acc += c5 * w5; acc += c6 * w6; acc += c7 * w7;
        }
        for (; j < n; ++j) {
            acc += __shfl(cf, j) * WhB[__shfl(dst, j) * DD + lane];
        }
    }
    out[(size_t)wid * DD + lane] = acc * (1.0f / EFF);
}

extern "C" void kernel_launch(void* const* d_in, const int* in_sizes, int n_in,
                              void* d_out, int out_size, void* d_ws, size_t ws_size,
                              hipStream_t stream) {
    const float* Wh = (const float*)d_in[0];
    const int* eidx = (const int*)d_in[1];
    const float* evals = (const float*)d_in[2];
    float* out = (float*)d_out;

    // Workspace layout
    char* p = (char*)d_ws;
    int* cnt = (int*)p;       p += (size_t)BB * NN * sizeof(int);     // 32 KB
    int* wcnt = (int*)p;      p += (size_t)BB * NN * sizeof(int);     // 32 KB
    float4* rdT = (float4*)p; p += (size_t)BB * NN * sizeof(float4);  // 128 KB
    unsigned int* bucket = (unsigned int*)p;                          // 4 MiB

    const int T = 256;
    k_zero<<<(BB * NN + T - 1) / T, T, 0, stream>>>(cnt);
    k_scatter<<<(BB * NE + T - 1) / T, T, 0, stream>>>(eidx, cnt, bucket);
    k_row_deg<<<(BB * NN) / 4, T, 0, stream>>>(evals, cnt, bucket, wcnt, rdT);
    k_row_out<<<(BB * NN) / 4, T, 0, stream>>>(evals, bucket, wcnt, rdT, Wh, out);
}